// Round 1
// baseline (1190.278 us; speedup 1.0000x reference)
//
#include <hip/hip_runtime.h>
#include <math.h>

// ---------------------------------------------------------------------------
// Moondream3Attention on MI355X (gfx950)
// T=2048, DIM=2048, H=32, HD=64, ROT=32, QKV_DIM=6144
// Pipeline:
//   1) qkv = hidden @ Wqkv^T + bqkv              (bf16 MFMA GEMM, 128x128 tile)
//   2) tok = gelu(qkv) @ [tau_wq;tau_wv]^T       (bf16 MFMA GEMM, 64x64, gelu fused)
//   3) qkv_process: tau gating + RoPE -> q,k [h][t][64] bf16, v^T [h][d][s] bf16
//   4) flash attention (online softmax, MFMA QK^T and PV)
//   5) out = attn @ Wout^T + bout                (bf16 MFMA GEMM)
// Workspace layout (bytes):
//   qkv      f32  [2048][6144]   @ 0         (50331648)
//   tok_raw  f32  [2048][64]     @ 50331648  (524288)
//   twstack  f32  [64][6144]     @ 50855936  (1572864)
//   qh       bf16 [32][2048][64] @ 52428800  (8388608)
//   kh       bf16 [32][2048][64] @ 60817408  (8388608)
//   vtb      bf16 [32][64][2048] @ 69206016  (8388608)
//   attn     f32  [2048][2048]   @ 77594624  (16777216)  -> total 94371840
// ---------------------------------------------------------------------------

typedef __bf16 bf16x8 __attribute__((ext_vector_type(8)));
typedef float floatx4 __attribute__((ext_vector_type(4)));

__device__ __forceinline__ unsigned short f2b(float x) {
    unsigned int b = __float_as_uint(x);
    b = b + 0x7FFFu + ((b >> 16) & 1u);   // round-to-nearest-even
    return (unsigned short)(b >> 16);
}

__device__ __forceinline__ float gelu_f(float x) {
    return 0.5f * x * (1.0f + erff(x * 0.70710678118654752440f));
}

__device__ __forceinline__ floatx4 mfma16(bf16x8 a, bf16x8 b, floatx4 c) {
    return __builtin_amdgcn_mfma_f32_16x16x32_bf16(a, b, c, 0, 0, 0);
}

// inv_freq[i] = 1e6^(-i/16), i = 0..15
__constant__ float INV_FREQ[16] = {
    1.0f, 0.42169650342858224f, 0.17782794100389228f, 0.074989420933245582f,
    0.031622776601683791f, 0.013335214321633240f, 0.0056234132519034908f,
    0.0023713737056616552f, 0.001f, 4.2169650342858224e-4f,
    1.7782794100389228e-4f, 7.4989420933245582e-5f, 3.1622776601683791e-5f,
    1.3335214321633240e-5f, 5.6234132519034908e-6f, 2.3713737056616552e-6f
};

// ---------------------------------------------------------------------------
// GEMM: C[M,N] = A[M,K] @ B[N,K]^T (+ bias[N]), optional gelu on A.
// fp32 global inputs, converted to bf16 during LDS staging.
// Block: 256 threads = 4 waves arranged 2x2, each wave does (BM/2)x(BN/2).
// ---------------------------------------------------------------------------
template <int BM, int BN, bool GELU_A, bool HAS_BIAS>
__global__ __launch_bounds__(256) void gemm_bt(
    const float* __restrict__ A, const float* __restrict__ B,
    const float* __restrict__ bias, float* __restrict__ C,
    int M, int N, int K) {
    constexpr int LDT = 72;              // LDS row stride (bf16 elems): 144 B, 16B-aligned, 2-way-max banks
    constexpr int MT = BM / 32, NT = BN / 32;
    __shared__ unsigned short As[BM * LDT];
    __shared__ unsigned short Bs[BN * LDT];

    const int tid = threadIdx.x;
    const int wave = tid >> 6, lane = tid & 63;
    const int row16 = lane & 15, quad = lane >> 4;
    const int wm = (wave >> 1) * (BM / 2), wn = (wave & 1) * (BN / 2);
    const int bm0 = blockIdx.y * BM, bn0 = blockIdx.x * BN;

    floatx4 acc[MT][NT] = {};

    for (int k0 = 0; k0 < K; k0 += 64) {
        // stage A (BM x 64 fp32 -> bf16)
        #pragma unroll
        for (int it = 0; it < BM / 16; ++it) {
            int i = tid + it * 256;
            int r = i >> 4, c4 = i & 15;
            float4 v = *reinterpret_cast<const float4*>(A + (size_t)(bm0 + r) * K + k0 + c4 * 4);
            if (GELU_A) { v.x = gelu_f(v.x); v.y = gelu_f(v.y); v.z = gelu_f(v.z); v.w = gelu_f(v.w); }
            ushort4 hh; hh.x = f2b(v.x); hh.y = f2b(v.y); hh.z = f2b(v.z); hh.w = f2b(v.w);
            *reinterpret_cast<ushort4*>(&As[r * LDT + c4 * 4]) = hh;
        }
        // stage B (BN x 64)
        #pragma unroll
        for (int it = 0; it < BN / 16; ++it) {
            int i = tid + it * 256;
            int r = i >> 4, c4 = i & 15;
            float4 v = *reinterpret_cast<const float4*>(B + (size_t)(bn0 + r) * K + k0 + c4 * 4);
            ushort4 hh; hh.x = f2b(v.x); hh.y = f2b(v.y); hh.z = f2b(v.z); hh.w = f2b(v.w);
            *reinterpret_cast<ushort4*>(&Bs[r * LDT + c4 * 4]) = hh;
        }
        __syncthreads();

        #pragma unroll
        for (int ks = 0; ks < 2; ++ks) {
            bf16x8 af[MT], bf[NT];
            #pragma unroll
            for (int mt = 0; mt < MT; ++mt)
                af[mt] = *reinterpret_cast<const bf16x8*>(&As[(wm + mt * 16 + row16) * LDT + ks * 32 + quad * 8]);
            #pragma unroll
            for (int nt = 0; nt < NT; ++nt)
                bf[nt] = *reinterpret_cast<const bf16x8*>(&Bs[(wn + nt * 16 + row16) * LDT + ks * 32 + quad * 8]);
            #pragma unroll
            for (int mt = 0; mt < MT; ++mt)
                #pragma unroll
                for (int nt = 0; nt < NT; ++nt)
                    acc[mt][nt] = mfma16(af[mt], bf[nt], acc[mt][nt]);
        }
        __syncthreads();
    }

    // epilogue: C/D layout col=lane&15, row=quad*4+i
    #pragma unroll
    for (int mt = 0; mt < MT; ++mt) {
        #pragma unroll
        for (int nt = 0; nt < NT; ++nt) {
            int gc = bn0 + wn + nt * 16 + row16;
            float bv = HAS_BIAS ? bias[gc] : 0.0f;
            int gr0 = bm0 + wm + mt * 16 + quad * 4;
            #pragma unroll
            for (int i = 0; i < 4; ++i)
                C[(size_t)(gr0 + i) * N + gc] = acc[mt][nt][i] + bv;
        }
    }
}

// ---------------------------------------------------------------------------
// Per-token/head processing: tau gating, RoPE, layout transforms.
// Block = (64 tokens, 1 head), 256 threads.
// ---------------------------------------------------------------------------
__global__ __launch_bounds__(256) void qkv_process(
    const float* __restrict__ qkv, const float* __restrict__ tok_raw,
    const float* __restrict__ tau_alpha, const int* __restrict__ positions,
    unsigned short* __restrict__ qh, unsigned short* __restrict__ kh,
    unsigned short* __restrict__ vtb) {
    const int h = blockIdx.y;
    const int t0 = blockIdx.x * 64;
    const int tid = threadIdx.x;
    __shared__ float vtr[64][65];
    __shared__ float tauq_s[64], tauv_s[64];

    if (tid < 64) {
        int t = t0 + tid;
        float pos = (float)positions[t];
        float pl = logf(fmaxf(pos + 1.0f, 1e-6f));
        float a = tau_alpha[h];
        float tp = 0.5f + 1.0f / (1.0f + __expf(-a * pl));
        tauq_s[tid] = tanhf(tok_raw[t * 64 + h]) + tp;
        tauv_s[tid] = tanhf(tok_raw[t * 64 + 32 + h]) + tp;
    }
    __syncthreads();

    #pragma unroll 4
    for (int it = 0; it < 16; ++it) {
        int i = tid + it * 256;
        int tl = i >> 6, d = i & 63;
        int t = t0 + tl;
        const float* row = qkv + (size_t)t * 6144 + h * 64;
        float qv = row[d];
        float kv = row[2048 + d];
        float vv = row[4096 + d];
        float tq = tauq_s[tl];
        float qo = qv * tq, ko = kv;
        if (d < 32) {
            int fi = d & 15;
            float ang = (float)positions[t] * INV_FREQ[fi];
            float s, c;
            sincosf(ang, &s, &c);
            float qp = row[d ^ 16] * tq;
            float kp = row[2048 + (d ^ 16)];
            if (d < 16) { qo = qv * tq * c - qp * s; ko = kv * c - kp * s; }
            else        { qo = qv * tq * c + qp * s; ko = kv * c + kp * s; }
        }
        size_t ob = ((size_t)h * 2048 + t) * 64 + d;
        qh[ob] = f2b(qo);
        kh[ob] = f2b(ko);
        vtr[d][tl] = vv * tauv_s[tl];
    }
    __syncthreads();
    #pragma unroll 4
    for (int it = 0; it < 16; ++it) {
        int i = tid + it * 256;
        int d = i >> 6, tl = i & 63;
        vtb[((size_t)h * 64 + d) * 2048 + t0 + tl] = f2b(vtr[d][tl]);
    }
}

// ---------------------------------------------------------------------------
// Flash attention (causal, online softmax).
// Block = (64 q-rows, 1 head); wave w owns q-rows [q0+16w, q0+16w+16).
// Per 32-s step: QK^T (4 MFMA) -> scale/mask/online-softmax in C-layout regs
// -> P via LDS (C->A layout) -> PV (4 MFMA) into O.
// ---------------------------------------------------------------------------
__global__ __launch_bounds__(256) void attn_fa(
    const unsigned short* __restrict__ qh, const unsigned short* __restrict__ kh,
    const unsigned short* __restrict__ vtb, float* __restrict__ attn) {
    constexpr int PS = 40;   // P-buffer row stride (ushorts): 80 B, 16B-aligned, spreads banks
    __shared__ unsigned short pbuf[4][2][16 * PS];
    const int h = blockIdx.y, qb = blockIdx.x;
    const int q0 = qb * 64;
    const int wave = threadIdx.x >> 6, lane = threadIdx.x & 63;
    const int m = lane & 15, quad = lane >> 4;
    const int qrow0 = q0 + wave * 16;

    const unsigned short* qbase = qh + ((size_t)h * 2048 + qrow0 + m) * 64;
    bf16x8 aq0 = *reinterpret_cast<const bf16x8*>(qbase + quad * 8);
    bf16x8 aq1 = *reinterpret_cast<const bf16x8*>(qbase + 32 + quad * 8);
    const unsigned short* kbase = kh + (size_t)h * 2048 * 64;
    const unsigned short* vbase = vtb + (size_t)h * 64 * 2048;

    floatx4 o[4] = {};
    float mrun[4], lrun[4];
    #pragma unroll
    for (int i = 0; i < 4; ++i) { mrun[i] = -__builtin_inff(); lrun[i] = 0.0f; }

    const int nsteps = (q0 + 64) / 32;
    for (int st = 0; st < nsteps; ++st) {
        const int s0 = st * 32;
        floatx4 sc[2];
        #pragma unroll
        for (int half = 0; half < 2; ++half) {
            const unsigned short* kr = kbase + (size_t)(s0 + half * 16 + m) * 64;
            bf16x8 bk0 = *reinterpret_cast<const bf16x8*>(kr + quad * 8);
            bf16x8 bk1 = *reinterpret_cast<const bf16x8*>(kr + 32 + quad * 8);
            floatx4 z = {};
            z = mfma16(aq0, bk0, z);
            z = mfma16(aq1, bk1, z);
            sc[half] = z;
        }
        float p0[4], p1[4], alpha[4], red[4];
        #pragma unroll
        for (int i = 0; i < 4; ++i) {
            int t = qrow0 + quad * 4 + i;
            float a = sc[0][i] * 0.125f;
            float b = sc[1][i] * 0.125f;
            a = ((s0 + m) > t) ? -__builtin_inff() : a;
            b = ((s0 + 16 + m) > t) ? -__builtin_inff() : b;
            sc[0][i] = a; sc[1][i] = b;
            red[i] = fmaxf(a, b);
        }
        #pragma unroll
        for (int i = 0; i < 4; ++i)
            #pragma unroll
            for (int d = 1; d < 16; d <<= 1)
                red[i] = fmaxf(red[i], __shfl_xor(red[i], d, 16));
        #pragma unroll
        for (int i = 0; i < 4; ++i) {
            float mnew = fmaxf(mrun[i], red[i]);
            alpha[i] = __expf(mrun[i] - mnew);
            p0[i] = (sc[0][i] == -__builtin_inff()) ? 0.0f : __expf(sc[0][i] - mnew);
            p1[i] = (sc[1][i] == -__builtin_inff()) ? 0.0f : __expf(sc[1][i] - mnew);
            mrun[i] = mnew;
            red[i] = p0[i] + p1[i];
        }
        #pragma unroll
        for (int i = 0; i < 4; ++i) {
            #pragma unroll
            for (int d = 1; d < 16; d <<= 1)
                red[i] += __shfl_xor(red[i], d, 16);
            lrun[i] = lrun[i] * alpha[i] + red[i];
        }
        #pragma unroll
        for (int nt = 0; nt < 4; ++nt)
            #pragma unroll
            for (int i = 0; i < 4; ++i)
                o[nt][i] *= alpha[i];

        // P: C-layout regs -> LDS -> A-layout frag (parity double-buffered)
        unsigned short* pb = pbuf[wave][st & 1];
        #pragma unroll
        for (int i = 0; i < 4; ++i) {
            pb[(quad * 4 + i) * PS + m] = f2b(p0[i]);
            pb[(quad * 4 + i) * PS + 16 + m] = f2b(p1[i]);
        }
        __syncthreads();
        bf16x8 ap = *reinterpret_cast<const bf16x8*>(&pbuf[wave][st & 1][m * PS + quad * 8]);

        #pragma unroll
        for (int nt = 0; nt < 4; ++nt) {
            const unsigned short* vr = vbase + (size_t)(nt * 16 + m) * 2048 + s0 + quad * 8;
            bf16x8 bv = *reinterpret_cast<const bf16x8*>(vr);
            o[nt] = mfma16(ap, bv, o[nt]);
        }
    }

    float invl[4];
    #pragma unroll
    for (int i = 0; i < 4; ++i) invl[i] = 1.0f / lrun[i];
    #pragma unroll
    for (int nt = 0; nt < 4; ++nt)
        #pragma unroll
        for (int i = 0; i < 4; ++i)
            attn[(size_t)(qrow0 + quad * 4 + i) * 2048 + h * 64 + nt * 16 + m] = o[nt][i] * invl[i];
}

// ---------------------------------------------------------------------------
extern "C" void kernel_launch(void* const* d_in, const int* in_sizes, int n_in,
                              void* d_out, int out_size, void* d_ws, size_t ws_size,
                              hipStream_t stream) {
    const int*   positions = (const int*)d_in[0];
    const float* hidden    = (const float*)d_in[1];
    const float* Wqkv      = (const float*)d_in[2];
    const float* bqkv      = (const float*)d_in[3];
    const float* Wout      = (const float*)d_in[4];
    const float* bout      = (const float*)d_in[5];
    const float* tau_alpha = (const float*)d_in[6];
    const float* tau_wq    = (const float*)d_in[7];
    const float* tau_wv    = (const float*)d_in[8];

    unsigned char* ws = (unsigned char*)d_ws;
    float*          qkv     = (float*)(ws);
    float*          tok_raw = (float*)(ws + 50331648);
    float*          twstack = (float*)(ws + 50855936);
    unsigned short* qh      = (unsigned short*)(ws + 52428800);
    unsigned short* kh      = (unsigned short*)(ws + 60817408);
    unsigned short* vtb     = (unsigned short*)(ws + 69206016);
    float*          attn    = (float*)(ws + 77594624);

    // stack [tau_wq; tau_wv] -> twstack [64][6144]
    hipMemcpyAsync(twstack, tau_wq, (size_t)32 * 6144 * 4, hipMemcpyDeviceToDevice, stream);
    hipMemcpyAsync(twstack + (size_t)32 * 6144, tau_wv, (size_t)32 * 6144 * 4, hipMemcpyDeviceToDevice, stream);

    // 1) qkv = hidden @ Wqkv^T + bqkv
    gemm_bt<128, 128, false, true><<<dim3(48, 16), 256, 0, stream>>>(
        hidden, Wqkv, bqkv, qkv, 2048, 6144, 2048);
    // 2) tok_raw = gelu(qkv) @ twstack^T
    gemm_bt<64, 64, true, false><<<dim3(1, 32), 256, 0, stream>>>(
        qkv, twstack, nullptr, tok_raw, 2048, 64, 6144);
    // 3) gating + RoPE + layout transforms
    qkv_process<<<dim3(32, 32), 256, 0, stream>>>(
        qkv, tok_raw, tau_alpha, positions, qh, kh, vtb);
    // 4) flash attention
    attn_fa<<<dim3(32, 32), 256, 0, stream>>>(qh, kh, vtb, attn);
    // 5) out = attn @ Wout^T + bout
    gemm_bt<128, 128, false, true><<<dim3(16, 16), 256, 0, stream>>>(
        attn, Wout, bout, (float*)d_out, 2048, 2048, 2048);
}

// Round 2
// 850.811 us; speedup vs baseline: 1.3990x; 1.3990x over previous
//
#include <hip/hip_runtime.h>
#include <math.h>

// ---------------------------------------------------------------------------
// Moondream3Attention on MI355X (gfx950)
// T=2048, DIM=2048, H=32, HD=64, ROT=32, QKV_DIM=6144
// Pipeline:
//   1) qkv = hidden @ Wqkv^T + bqkv              (bf16 MFMA GEMM, 128x128 tile)
//   2) tok = gelu(qkv) @ [tau_wq;tau_wv]^T       (split-K bf16 MFMA GEMM + atomic reduce)
//   3) qkv_process: tau gating + RoPE -> q,k [h][t][64] bf16, v^T [h][d][s] bf16
//   4) flash attention (online softmax, MFMA QK^T and PV)
//   5) out = attn @ Wout^T + bout                (bf16 MFMA GEMM)
// Workspace layout (bytes):
//   qkv      f32  [2048][6144]   @ 0         (50331648)
//   tok_raw  f32  [2048][64]     @ 50331648  (524288)
//   qh       bf16 [32][2048][64] @ 52428800  (8388608)
//   kh       bf16 [32][2048][64] @ 60817408  (8388608)
//   vtb      bf16 [32][64][2048] @ 69206016  (8388608)
//   attn     f32  [2048][2048]   @ 77594624  (16777216)  -> total 94371840
// ---------------------------------------------------------------------------

typedef __bf16 bf16x8 __attribute__((ext_vector_type(8)));
typedef float floatx4 __attribute__((ext_vector_type(4)));

__device__ __forceinline__ unsigned short f2b(float x) {
    unsigned int b = __float_as_uint(x);
    b = b + 0x7FFFu + ((b >> 16) & 1u);   // round-to-nearest-even
    return (unsigned short)(b >> 16);
}

__device__ __forceinline__ float gelu_f(float x) {
    return 0.5f * x * (1.0f + erff(x * 0.70710678118654752440f));
}

__device__ __forceinline__ floatx4 mfma16(bf16x8 a, bf16x8 b, floatx4 c) {
    return __builtin_amdgcn_mfma_f32_16x16x32_bf16(a, b, c, 0, 0, 0);
}

// inv_freq[i] = 1e6^(-i/16), i = 0..15
__constant__ float INV_FREQ[16] = {
    1.0f, 0.42169650342858224f, 0.17782794100389228f, 0.074989420933245582f,
    0.031622776601683791f, 0.013335214321633240f, 0.0056234132519034908f,
    0.0023713737056616552f, 0.001f, 4.2169650342858224e-4f,
    1.7782794100389228e-4f, 7.4989420933245582e-5f, 3.1622776601683791e-5f,
    1.3335214321633240e-5f, 5.6234132519034908e-6f, 2.3713737056616552e-6f
};

// ---------------------------------------------------------------------------
// GEMM: C[M,N] = A[M,K] @ B[N,K]^T (+ bias[N]).
// fp32 global inputs, converted to bf16 during LDS staging.
// Block: 256 threads = 4 waves arranged 2x2, each wave does (BM/2)x(BN/2).
// ---------------------------------------------------------------------------
template <int BM, int BN, bool HAS_BIAS>
__global__ __launch_bounds__(256) void gemm_bt(
    const float* __restrict__ A, const float* __restrict__ B,
    const float* __restrict__ bias, float* __restrict__ C,
    int M, int N, int K) {
    constexpr int LDT = 72;              // LDS row stride (bf16 elems): 144 B, 16B-aligned, 2-way-max banks
    constexpr int MT = BM / 32, NT = BN / 32;
    __shared__ unsigned short As[BM * LDT];
    __shared__ unsigned short Bs[BN * LDT];

    const int tid = threadIdx.x;
    const int wave = tid >> 6, lane = tid & 63;
    const int row16 = lane & 15, quad = lane >> 4;
    const int wm = (wave >> 1) * (BM / 2), wn = (wave & 1) * (BN / 2);
    const int bm0 = blockIdx.y * BM, bn0 = blockIdx.x * BN;

    floatx4 acc[MT][NT] = {};

    for (int k0 = 0; k0 < K; k0 += 64) {
        // stage A (BM x 64 fp32 -> bf16)
        #pragma unroll
        for (int it = 0; it < BM / 16; ++it) {
            int i = tid + it * 256;
            int r = i >> 4, c4 = i & 15;
            float4 v = *reinterpret_cast<const float4*>(A + (size_t)(bm0 + r) * K + k0 + c4 * 4);
            ushort4 hh; hh.x = f2b(v.x); hh.y = f2b(v.y); hh.z = f2b(v.z); hh.w = f2b(v.w);
            *reinterpret_cast<ushort4*>(&As[r * LDT + c4 * 4]) = hh;
        }
        // stage B (BN x 64)
        #pragma unroll
        for (int it = 0; it < BN / 16; ++it) {
            int i = tid + it * 256;
            int r = i >> 4, c4 = i & 15;
            float4 v = *reinterpret_cast<const float4*>(B + (size_t)(bn0 + r) * K + k0 + c4 * 4);
            ushort4 hh; hh.x = f2b(v.x); hh.y = f2b(v.y); hh.z = f2b(v.z); hh.w = f2b(v.w);
            *reinterpret_cast<ushort4*>(&Bs[r * LDT + c4 * 4]) = hh;
        }
        __syncthreads();

        #pragma unroll
        for (int ks = 0; ks < 2; ++ks) {
            bf16x8 af[MT], bfr[NT];
            #pragma unroll
            for (int mt = 0; mt < MT; ++mt)
                af[mt] = *reinterpret_cast<const bf16x8*>(&As[(wm + mt * 16 + row16) * LDT + ks * 32 + quad * 8]);
            #pragma unroll
            for (int nt = 0; nt < NT; ++nt)
                bfr[nt] = *reinterpret_cast<const bf16x8*>(&Bs[(wn + nt * 16 + row16) * LDT + ks * 32 + quad * 8]);
            #pragma unroll
            for (int mt = 0; mt < MT; ++mt)
                #pragma unroll
                for (int nt = 0; nt < NT; ++nt)
                    acc[mt][nt] = mfma16(af[mt], bfr[nt], acc[mt][nt]);
        }
        __syncthreads();
    }

    // epilogue: C/D layout col=lane&15, row=quad*4+i
    #pragma unroll
    for (int mt = 0; mt < MT; ++mt) {
        #pragma unroll
        for (int nt = 0; nt < NT; ++nt) {
            int gc = bn0 + wn + nt * 16 + row16;
            float bv = HAS_BIAS ? bias[gc] : 0.0f;
            int gr0 = bm0 + wm + mt * 16 + quad * 4;
            #pragma unroll
            for (int i = 0; i < 4; ++i)
                C[(size_t)(gr0 + i) * N + gc] = acc[mt][nt][i] + bv;
        }
    }
}

// ---------------------------------------------------------------------------
// tok GEMM, split-K: C[2048,64] += gelu(A[2048,6144]) @ [Bq;Bv][64,6144]^T.
// Grid: (K/KSPLIT, M/64). Each block does a 64x64xKSPLIT partial, atomicAdds.
// C must be pre-zeroed.
// ---------------------------------------------------------------------------
template <int KSPLIT>
__global__ __launch_bounds__(256) void tok_gemm_splitk(
    const float* __restrict__ A, const float* __restrict__ Bq,
    const float* __restrict__ Bv, float* __restrict__ C, int K) {
    constexpr int LDT = 72;
    __shared__ unsigned short As[64 * LDT];
    __shared__ unsigned short Bs[64 * LDT];

    const int tid = threadIdx.x;
    const int wave = tid >> 6, lane = tid & 63;
    const int row16 = lane & 15, quad = lane >> 4;
    const int wm = (wave >> 1) * 32, wn = (wave & 1) * 32;
    const int bm0 = blockIdx.y * 64;
    const int kbeg = blockIdx.x * KSPLIT;

    floatx4 acc[2][2] = {};

    for (int k0 = kbeg; k0 < kbeg + KSPLIT; k0 += 64) {
        #pragma unroll
        for (int it = 0; it < 4; ++it) {
            int i = tid + it * 256;
            int r = i >> 4, c4 = i & 15;
            float4 v = *reinterpret_cast<const float4*>(A + (size_t)(bm0 + r) * K + k0 + c4 * 4);
            v.x = gelu_f(v.x); v.y = gelu_f(v.y); v.z = gelu_f(v.z); v.w = gelu_f(v.w);
            ushort4 hh; hh.x = f2b(v.x); hh.y = f2b(v.y); hh.z = f2b(v.z); hh.w = f2b(v.w);
            *reinterpret_cast<ushort4*>(&As[r * LDT + c4 * 4]) = hh;

            const float* brow = (r < 32) ? (Bq + (size_t)r * K) : (Bv + (size_t)(r - 32) * K);
            float4 w = *reinterpret_cast<const float4*>(brow + k0 + c4 * 4);
            ushort4 wh; wh.x = f2b(w.x); wh.y = f2b(w.y); wh.z = f2b(w.z); wh.w = f2b(w.w);
            *reinterpret_cast<ushort4*>(&Bs[r * LDT + c4 * 4]) = wh;
        }
        __syncthreads();

        #pragma unroll
        for (int ks = 0; ks < 2; ++ks) {
            bf16x8 af[2], bfr[2];
            #pragma unroll
            for (int mt = 0; mt < 2; ++mt)
                af[mt] = *reinterpret_cast<const bf16x8*>(&As[(wm + mt * 16 + row16) * LDT + ks * 32 + quad * 8]);
            #pragma unroll
            for (int nt = 0; nt < 2; ++nt)
                bfr[nt] = *reinterpret_cast<const bf16x8*>(&Bs[(wn + nt * 16 + row16) * LDT + ks * 32 + quad * 8]);
            #pragma unroll
            for (int mt = 0; mt < 2; ++mt)
                #pragma unroll
                for (int nt = 0; nt < 2; ++nt)
                    acc[mt][nt] = mfma16(af[mt], bfr[nt], acc[mt][nt]);
        }
        __syncthreads();
    }

    #pragma unroll
    for (int mt = 0; mt < 2; ++mt)
        #pragma unroll
        for (int nt = 0; nt < 2; ++nt) {
            int gc = wn + nt * 16 + row16;
            int gr0 = bm0 + wm + mt * 16 + quad * 4;
            #pragma unroll
            for (int i = 0; i < 4; ++i)
                atomicAdd(&C[(size_t)(gr0 + i) * 64 + gc], acc[mt][nt][i]);
        }
}

// ---------------------------------------------------------------------------
// Per-token/head processing: tau gating, RoPE, layout transforms.
// Block = (64 tokens, 1 head), 256 threads.
// ---------------------------------------------------------------------------
__global__ __launch_bounds__(256) void qkv_process(
    const float* __restrict__ qkv, const float* __restrict__ tok_raw,
    const float* __restrict__ tau_alpha, const int* __restrict__ positions,
    unsigned short* __restrict__ qh, unsigned short* __restrict__ kh,
    unsigned short* __restrict__ vtb) {
    const int h = blockIdx.y;
    const int t0 = blockIdx.x * 64;
    const int tid = threadIdx.x;
    __shared__ float vtr[64][65];
    __shared__ float tauq_s[64], tauv_s[64];

    if (tid < 64) {
        int t = t0 + tid;
        float pos = (float)positions[t];
        float pl = logf(fmaxf(pos + 1.0f, 1e-6f));
        float a = tau_alpha[h];
        float tp = 0.5f + 1.0f / (1.0f + __expf(-a * pl));
        tauq_s[tid] = tanhf(tok_raw[t * 64 + h]) + tp;
        tauv_s[tid] = tanhf(tok_raw[t * 64 + 32 + h]) + tp;
    }
    __syncthreads();

    #pragma unroll 4
    for (int it = 0; it < 16; ++it) {
        int i = tid + it * 256;
        int tl = i >> 6, d = i & 63;
        int t = t0 + tl;
        const float* row = qkv + (size_t)t * 6144 + h * 64;
        float qv = row[d];
        float kv = row[2048 + d];
        float vv = row[4096 + d];
        float tq = tauq_s[tl];
        float qo = qv * tq, ko = kv;
        if (d < 32) {
            int fi = d & 15;
            float ang = (float)positions[t] * INV_FREQ[fi];
            float s, c;
            sincosf(ang, &s, &c);
            float qp = row[d ^ 16] * tq;
            float kp = row[2048 + (d ^ 16)];
            if (d < 16) { qo = qv * tq * c - qp * s; ko = kv * c - kp * s; }
            else        { qo = qv * tq * c + qp * s; ko = kv * c + kp * s; }
        }
        size_t ob = ((size_t)h * 2048 + t) * 64 + d;
        qh[ob] = f2b(qo);
        kh[ob] = f2b(ko);
        vtr[d][tl] = vv * tauv_s[tl];
    }
    __syncthreads();
    #pragma unroll 4
    for (int it = 0; it < 16; ++it) {
        int i = tid + it * 256;
        int d = i >> 6, tl = i & 63;
        vtb[((size_t)h * 64 + d) * 2048 + t0 + tl] = f2b(vtr[d][tl]);
    }
}

// ---------------------------------------------------------------------------
// Flash attention (causal, online softmax).
// Block = (64 q-rows, 1 head); wave w owns q-rows [q0+16w, q0+16w+16).
// ---------------------------------------------------------------------------
__global__ __launch_bounds__(256) void attn_fa(
    const unsigned short* __restrict__ qh, const unsigned short* __restrict__ kh,
    const unsigned short* __restrict__ vtb, float* __restrict__ attn) {
    constexpr int PS = 40;   // P-buffer row stride (ushorts): 80 B, 16B-aligned, spreads banks
    __shared__ unsigned short pbuf[4][2][16 * PS];
    const int h = blockIdx.y, qb = blockIdx.x;
    const int q0 = qb * 64;
    const int wave = threadIdx.x >> 6, lane = threadIdx.x & 63;
    const int m = lane & 15, quad = lane >> 4;
    const int qrow0 = q0 + wave * 16;

    const unsigned short* qbase = qh + ((size_t)h * 2048 + qrow0 + m) * 64;
    bf16x8 aq0 = *reinterpret_cast<const bf16x8*>(qbase + quad * 8);
    bf16x8 aq1 = *reinterpret_cast<const bf16x8*>(qbase + 32 + quad * 8);
    const unsigned short* kbase = kh + (size_t)h * 2048 * 64;
    const unsigned short* vbase = vtb + (size_t)h * 64 * 2048;

    floatx4 o[4] = {};
    float mrun[4], lrun[4];
    #pragma unroll
    for (int i = 0; i < 4; ++i) { mrun[i] = -__builtin_inff(); lrun[i] = 0.0f; }

    const int nsteps = (q0 + 64) / 32;
    for (int st = 0; st < nsteps; ++st) {
        const int s0 = st * 32;
        floatx4 sc[2];
        #pragma unroll
        for (int half = 0; half < 2; ++half) {
            const unsigned short* kr = kbase + (size_t)(s0 + half * 16 + m) * 64;
            bf16x8 bk0 = *reinterpret_cast<const bf16x8*>(kr + quad * 8);
            bf16x8 bk1 = *reinterpret_cast<const bf16x8*>(kr + 32 + quad * 8);
            floatx4 z = {};
            z = mfma16(aq0, bk0, z);
            z = mfma16(aq1, bk1, z);
            sc[half] = z;
        }
        float p0[4], p1[4], alpha[4], red[4];
        #pragma unroll
        for (int i = 0; i < 4; ++i) {
            int t = qrow0 + quad * 4 + i;
            float a = sc[0][i] * 0.125f;
            float b = sc[1][i] * 0.125f;
            a = ((s0 + m) > t) ? -__builtin_inff() : a;
            b = ((s0 + 16 + m) > t) ? -__builtin_inff() : b;
            sc[0][i] = a; sc[1][i] = b;
            red[i] = fmaxf(a, b);
        }
        #pragma unroll
        for (int i = 0; i < 4; ++i)
            #pragma unroll
            for (int d = 1; d < 16; d <<= 1)
                red[i] = fmaxf(red[i], __shfl_xor(red[i], d, 16));
        #pragma unroll
        for (int i = 0; i < 4; ++i) {
            float mnew = fmaxf(mrun[i], red[i]);
            alpha[i] = __expf(mrun[i] - mnew);
            p0[i] = (sc[0][i] == -__builtin_inff()) ? 0.0f : __expf(sc[0][i] - mnew);
            p1[i] = (sc[1][i] == -__builtin_inff()) ? 0.0f : __expf(sc[1][i] - mnew);
            mrun[i] = mnew;
            red[i] = p0[i] + p1[i];
        }
        #pragma unroll
        for (int i = 0; i < 4; ++i) {
            #pragma unroll
            for (int d = 1; d < 16; d <<= 1)
                red[i] += __shfl_xor(red[i], d, 16);
            lrun[i] = lrun[i] * alpha[i] + red[i];
        }
        #pragma unroll
        for (int nt = 0; nt < 4; ++nt)
            #pragma unroll
            for (int i = 0; i < 4; ++i)
                o[nt][i] *= alpha[i];

        // P: C-layout regs -> LDS -> A-layout frag (parity double-buffered)
        unsigned short* pb = pbuf[wave][st & 1];
        #pragma unroll
        for (int i = 0; i < 4; ++i) {
            pb[(quad * 4 + i) * PS + m] = f2b(p0[i]);
            pb[(quad * 4 + i) * PS + 16 + m] = f2b(p1[i]);
        }
        __syncthreads();
        bf16x8 ap = *reinterpret_cast<const bf16x8*>(&pbuf[wave][st & 1][m * PS + quad * 8]);

        #pragma unroll
        for (int nt = 0; nt < 4; ++nt) {
            const unsigned short* vr = vbase + (size_t)(nt * 16 + m) * 2048 + s0 + quad * 8;
            bf16x8 bv = *reinterpret_cast<const bf16x8*>(vr);
            o[nt] = mfma16(ap, bv, o[nt]);
        }
    }

    float invl[4];
    #pragma unroll
    for (int i = 0; i < 4; ++i) invl[i] = 1.0f / lrun[i];
    #pragma unroll
    for (int nt = 0; nt < 4; ++nt)
        #pragma unroll
        for (int i = 0; i < 4; ++i)
            attn[(size_t)(qrow0 + quad * 4 + i) * 2048 + h * 64 + nt * 16 + m] = o[nt][i] * invl[i];
}

// ---------------------------------------------------------------------------
extern "C" void kernel_launch(void* const* d_in, const int* in_sizes, int n_in,
                              void* d_out, int out_size, void* d_ws, size_t ws_size,
                              hipStream_t stream) {
    const int*   positions = (const int*)d_in[0];
    const float* hidden    = (const float*)d_in[1];
    const float* Wqkv      = (const float*)d_in[2];
    const float* bqkv      = (const float*)d_in[3];
    const float* Wout      = (const float*)d_in[4];
    const float* bout      = (const float*)d_in[5];
    const float* tau_alpha = (const float*)d_in[6];
    const float* tau_wq    = (const float*)d_in[7];
    const float* tau_wv    = (const float*)d_in[8];

    unsigned char* ws = (unsigned char*)d_ws;
    float*          qkv     = (float*)(ws);
    float*          tok_raw = (float*)(ws + 50331648);
    unsigned short* qh      = (unsigned short*)(ws + 52428800);
    unsigned short* kh      = (unsigned short*)(ws + 60817408);
    unsigned short* vtb     = (unsigned short*)(ws + 69206016);
    float*          attn    = (float*)(ws + 77594624);

    // 1) qkv = hidden @ Wqkv^T + bqkv
    gemm_bt<128, 128, true><<<dim3(48, 16), 256, 0, stream>>>(
        hidden, Wqkv, bqkv, qkv, 2048, 6144, 2048);
    // 2) tok_raw = gelu(qkv) @ [tau_wq;tau_wv]^T   (split-K, 24 x 256)
    hipMemsetAsync(tok_raw, 0, (size_t)2048 * 64 * 4, stream);
    tok_gemm_splitk<256><<<dim3(24, 32), 256, 0, stream>>>(
        qkv, tau_wq, tau_wv, tok_raw, 6144);
    // 3) gating + RoPE + layout transforms
    qkv_process<<<dim3(32, 32), 256, 0, stream>>>(
        qkv, tok_raw, tau_alpha, positions, qh, kh, vtb);
    // 4) flash attention
    attn_fa<<<dim3(32, 32), 256, 0, stream>>>(qh, kh, vtb, attn);
    // 5) out = attn @ Wout^T + bout
    gemm_bt<128, 128, true><<<dim3(16, 16), 256, 0, stream>>>(
        attn, Wout, bout, (float*)d_out, 2048, 2048, 2048);
}

// Round 3
// 487.404 us; speedup vs baseline: 2.4421x; 1.7456x over previous
//
#include <hip/hip_runtime.h>
#include <math.h>

// ---------------------------------------------------------------------------
// Moondream3Attention on MI355X (gfx950)
// T=2048, DIM=2048, H=32, HD=64, ROT=32, QKV_DIM=6144
// Pipeline (all-bf16 matmul datapath):
//   0) cvt: hidden->hb, Wqkv->wqb, Wout->wob (fp32->bf16)
//   1) qkvb = hb @ wqb^T + bqkv          (bf16 GEMM, global_load_lds staging)
//   2) tok = gelu(qkvb) @ [tau_wq;tau_wv]^T   (split-K + atomics)
//   3) qkv_process: tau gating + RoPE -> qh(k*1/8),kh [h][t][64], vtb [h][d][s]
//   4) attn_fa: barrier-free flash attention -> attnb bf16 [t][2048]
//   5) out = attnb @ wob^T + bout        (bf16 GEMM, fp32 out)
// Workspace (bytes):
//   qkvb    bf16 [2048][6144]  @ 0         (25165824)
//   tok_raw f32  [2048][64]    @ 25165824  (524288)
//   wqb     bf16 [6144][2048]  @ 25690112  (25165824)  dead after GEMM1, then:
//     qh    bf16 [32][2048][64]@ 25690112  (8388608)
//     kh    bf16 [32][2048][64]@ 34078720  (8388608)
//     vtb   bf16 [32][64][2048]@ 42467328  (8388608)
//   attnb   bf16 [2048][2048]  @ 50855936  (8388608)
//   hb      bf16 [2048][2048]  @ 59244544  (8388608)
//   wob     bf16 [2048][2048]  @ 67633152  (8388608)   total 76021760
// ---------------------------------------------------------------------------

typedef __bf16 bf16x8 __attribute__((ext_vector_type(8)));
typedef float floatx4 __attribute__((ext_vector_type(4)));
typedef unsigned short ushort8v __attribute__((ext_vector_type(8)));

__device__ __forceinline__ unsigned short f2b(float x) {
    unsigned int b = __float_as_uint(x);
    b = b + 0x7FFFu + ((b >> 16) & 1u);   // round-to-nearest-even
    return (unsigned short)(b >> 16);
}
__device__ __forceinline__ float b2f(unsigned short u) {
    return __uint_as_float(((unsigned int)u) << 16);
}
__device__ __forceinline__ float gelu_f(float x) {
    return 0.5f * x * (1.0f + erff(x * 0.70710678118654752440f));
}
__device__ __forceinline__ floatx4 mfma16(bf16x8 a, bf16x8 b, floatx4 c) {
    return __builtin_amdgcn_mfma_f32_16x16x32_bf16(a, b, c, 0, 0, 0);
}
// async global->LDS, 16B per lane; lane i lands at ldsbase + i*16
__device__ __forceinline__ void gl2lds16(const unsigned short* g, unsigned short* l) {
    __builtin_amdgcn_global_load_lds(
        (__attribute__((address_space(1))) void*)g,
        (__attribute__((address_space(3))) void*)l, 16, 0, 0);
}

// inv_freq[i] = 1e6^(-i/16), i = 0..15
__constant__ float INV_FREQ[16] = {
    1.0f, 0.42169650342858224f, 0.17782794100389228f, 0.074989420933245582f,
    0.031622776601683791f, 0.013335214321633240f, 0.0056234132519034908f,
    0.0023713737056616552f, 0.001f, 4.2169650342858224e-4f,
    1.7782794100389228e-4f, 7.4989420933245582e-5f, 3.1622776601683791e-5f,
    1.3335214321633240e-5f, 5.6234132519034908e-6f, 2.3713737056616552e-6f
};

// ---------------------------------------------------------------------------
__global__ __launch_bounds__(256) void cvt_f32_bf16(
    const float* __restrict__ src, unsigned short* __restrict__ dst, int n8) {
    int i = blockIdx.x * 256 + threadIdx.x;
    if (i >= n8) return;
    const float4* s = reinterpret_cast<const float4*>(src) + (size_t)i * 2;
    float4 a = s[0], b = s[1];
    ushort8v r;
    r[0] = f2b(a.x); r[1] = f2b(a.y); r[2] = f2b(a.z); r[3] = f2b(a.w);
    r[4] = f2b(b.x); r[5] = f2b(b.y); r[6] = f2b(b.z); r[7] = f2b(b.w);
    *(reinterpret_cast<ushort8v*>(dst) + i) = r;
}

// ---------------------------------------------------------------------------
// bf16 GEMM: C[M,N] = A[M,K] @ B[N,K]^T + bias[N].  128x128 tile, BK=64.
// Staging via global_load_lds (16B/lane). LDS layout:
//   addr(r,c8) = (r>>3)*1024B + c8*128B + (r&7)*16B  (r=tile row, c8=k/8)
// -> frag ds_read_b128 has only 2-way bank aliasing (free, m136).
// ---------------------------------------------------------------------------
template <bool OUT_BF16>
__global__ __launch_bounds__(256) void gemm_bf16_bt(
    const unsigned short* __restrict__ A, const unsigned short* __restrict__ B,
    const float* __restrict__ bias, void* __restrict__ Cout,
    int M, int N, int K) {
    __shared__ unsigned short As[128 * 64];
    __shared__ unsigned short Bs[128 * 64];
    const int tid = threadIdx.x;
    const int wave = tid >> 6, lane = tid & 63;
    const int row16 = lane & 15, quad = lane >> 4;
    const int wm = (wave >> 1) * 64, wn = (wave & 1) * 64;
    const int bm0 = blockIdx.y * 128, bn0 = blockIdx.x * 128;
    const int rl = lane & 7, cl = lane >> 3;

    floatx4 acc[4][4] = {};

    for (int k0 = 0; k0 < K; k0 += 64) {
        __syncthreads();                       // prev iter's frag reads done
        #pragma unroll
        for (int j = 0; j < 4; ++j) {
            int inst = wave * 4 + j;           // covers tile rows inst*8..+8
            const unsigned short* ga = A + (size_t)(bm0 + inst * 8 + rl) * K + k0 + cl * 8;
            gl2lds16(ga, &As[inst * 512 + lane * 8]);
            const unsigned short* gb = B + (size_t)(bn0 + inst * 8 + rl) * K + k0 + cl * 8;
            gl2lds16(gb, &Bs[inst * 512 + lane * 8]);
        }
        __syncthreads();                       // drains vmcnt -> data landed

        #pragma unroll
        for (int ks = 0; ks < 2; ++ks) {
            bf16x8 af[4], bfr[4];
            #pragma unroll
            for (int mt = 0; mt < 4; ++mt) {
                int r = wm + mt * 16 + row16;
                af[mt] = *reinterpret_cast<const bf16x8*>(
                    &As[(r >> 3) * 512 + (ks * 4 + quad) * 64 + (r & 7) * 8]);
            }
            #pragma unroll
            for (int nt = 0; nt < 4; ++nt) {
                int r = wn + nt * 16 + row16;
                bfr[nt] = *reinterpret_cast<const bf16x8*>(
                    &Bs[(r >> 3) * 512 + (ks * 4 + quad) * 64 + (r & 7) * 8]);
            }
            #pragma unroll
            for (int mt = 0; mt < 4; ++mt)
                #pragma unroll
                for (int nt = 0; nt < 4; ++nt)
                    acc[mt][nt] = mfma16(af[mt], bfr[nt], acc[mt][nt]);
        }
    }

    #pragma unroll
    for (int mt = 0; mt < 4; ++mt) {
        #pragma unroll
        for (int nt = 0; nt < 4; ++nt) {
            int gc = bn0 + wn + nt * 16 + row16;
            float bv = bias[gc];
            int gr0 = bm0 + wm + mt * 16 + quad * 4;
            #pragma unroll
            for (int i = 0; i < 4; ++i) {
                float v = acc[mt][nt][i] + bv;
                if (OUT_BF16)
                    ((unsigned short*)Cout)[(size_t)(gr0 + i) * N + gc] = f2b(v);
                else
                    ((float*)Cout)[(size_t)(gr0 + i) * N + gc] = v;
            }
        }
    }
}

// ---------------------------------------------------------------------------
// tok GEMM split-K: C[2048,64] += gelu(qkvb) @ [Bq;Bv]^T; C pre-zeroed.
// ---------------------------------------------------------------------------
template <int KSPLIT>
__global__ __launch_bounds__(256) void tok_gemm_splitk(
    const unsigned short* __restrict__ A, const float* __restrict__ Bq,
    const float* __restrict__ Bv, float* __restrict__ C, int K) {
    constexpr int LDT = 72;
    __shared__ unsigned short As[64 * LDT];
    __shared__ unsigned short Bs[64 * LDT];
    const int tid = threadIdx.x;
    const int wave = tid >> 6, lane = tid & 63;
    const int row16 = lane & 15, quad = lane >> 4;
    const int wm = (wave >> 1) * 32, wn = (wave & 1) * 32;
    const int bm0 = blockIdx.y * 64;
    const int kbeg = blockIdx.x * KSPLIT;

    floatx4 acc[2][2] = {};

    for (int k0 = kbeg; k0 < kbeg + KSPLIT; k0 += 64) {
        #pragma unroll
        for (int it = 0; it < 2; ++it) {
            int i = tid + it * 256;
            int r = i >> 3, c8 = i & 7;
            ushort8v a = *reinterpret_cast<const ushort8v*>(
                A + (size_t)(bm0 + r) * K + k0 + c8 * 8);
            ushort8v g;
            #pragma unroll
            for (int j = 0; j < 8; ++j) g[j] = f2b(gelu_f(b2f(a[j])));
            *reinterpret_cast<ushort8v*>(&As[r * LDT + c8 * 8]) = g;

            const float* brow = (r < 32) ? (Bq + (size_t)r * K) : (Bv + (size_t)(r - 32) * K);
            float4 w0 = *reinterpret_cast<const float4*>(brow + k0 + c8 * 8);
            float4 w1 = *reinterpret_cast<const float4*>(brow + k0 + c8 * 8 + 4);
            ushort8v wb;
            wb[0] = f2b(w0.x); wb[1] = f2b(w0.y); wb[2] = f2b(w0.z); wb[3] = f2b(w0.w);
            wb[4] = f2b(w1.x); wb[5] = f2b(w1.y); wb[6] = f2b(w1.z); wb[7] = f2b(w1.w);
            *reinterpret_cast<ushort8v*>(&Bs[r * LDT + c8 * 8]) = wb;
        }
        __syncthreads();

        #pragma unroll
        for (int ks = 0; ks < 2; ++ks) {
            bf16x8 af[2], bfr[2];
            #pragma unroll
            for (int mt = 0; mt < 2; ++mt)
                af[mt] = *reinterpret_cast<const bf16x8*>(
                    &As[(wm + mt * 16 + row16) * LDT + ks * 32 + quad * 8]);
            #pragma unroll
            for (int nt = 0; nt < 2; ++nt)
                bfr[nt] = *reinterpret_cast<const bf16x8*>(
                    &Bs[(wn + nt * 16 + row16) * LDT + ks * 32 + quad * 8]);
            #pragma unroll
            for (int mt = 0; mt < 2; ++mt)
                #pragma unroll
                for (int nt = 0; nt < 2; ++nt)
                    acc[mt][nt] = mfma16(af[mt], bfr[nt], acc[mt][nt]);
        }
        __syncthreads();
    }

    #pragma unroll
    for (int mt = 0; mt < 2; ++mt)
        #pragma unroll
        for (int nt = 0; nt < 2; ++nt) {
            int gc = wn + nt * 16 + row16;
            int gr0 = bm0 + wm + mt * 16 + quad * 4;
            #pragma unroll
            for (int i = 0; i < 4; ++i)
                atomicAdd(&C[(size_t)(gr0 + i) * 64 + gc], acc[mt][nt][i]);
        }
}

// ---------------------------------------------------------------------------
// tau gating + RoPE + layout transforms (qkv now bf16; q pre-scaled by 1/8).
// ---------------------------------------------------------------------------
__global__ __launch_bounds__(256) void qkv_process(
    const unsigned short* __restrict__ qkvb, const float* __restrict__ tok_raw,
    const float* __restrict__ tau_alpha, const int* __restrict__ positions,
    unsigned short* __restrict__ qh, unsigned short* __restrict__ kh,
    unsigned short* __restrict__ vtb) {
    const int h = blockIdx.y;
    const int t0 = blockIdx.x * 64;
    const int tid = threadIdx.x;
    __shared__ float vtr[64][65];
    __shared__ float tauq_s[64], tauv_s[64];

    if (tid < 64) {
        int t = t0 + tid;
        float pos = (float)positions[t];
        float pl = logf(fmaxf(pos + 1.0f, 1e-6f));
        float a = tau_alpha[h];
        float tp = 0.5f + 1.0f / (1.0f + __expf(-a * pl));
        tauq_s[tid] = tanhf(tok_raw[t * 64 + h]) + tp;
        tauv_s[tid] = tanhf(tok_raw[t * 64 + 32 + h]) + tp;
    }
    __syncthreads();

    #pragma unroll 4
    for (int it = 0; it < 16; ++it) {
        int i = tid + it * 256;
        int tl = i >> 6, d = i & 63;
        int t = t0 + tl;
        const unsigned short* row = qkvb + (size_t)t * 6144 + h * 64;
        float qv = b2f(row[d]);
        float kv = b2f(row[2048 + d]);
        float vv = b2f(row[4096 + d]);
        float tq = tauq_s[tl];
        float qo = qv * tq, ko = kv;
        if (d < 32) {
            int fi = d & 15;
            float ang = (float)positions[t] * INV_FREQ[fi];
            float s, c;
            sincosf(ang, &s, &c);
            float qp = b2f(row[d ^ 16]) * tq;
            float kp = b2f(row[2048 + (d ^ 16)]);
            if (d < 16) { qo = qv * tq * c - qp * s; ko = kv * c - kp * s; }
            else        { qo = qv * tq * c + qp * s; ko = kv * c + kp * s; }
        }
        size_t ob = ((size_t)h * 2048 + t) * 64 + d;
        qh[ob] = f2b(qo * 0.125f);   // fold softmax scale into Q
        kh[ob] = f2b(ko);
        vtr[d][tl] = vv * tauv_s[tl];
    }
    __syncthreads();
    #pragma unroll 4
    for (int it = 0; it < 16; ++it) {
        int i = tid + it * 256;
        int d = i >> 6, tl = i & 63;
        vtb[((size_t)h * 64 + d) * 2048 + t0 + tl] = f2b(vtr[d][tl]);
    }
}

// ---------------------------------------------------------------------------
// Barrier-free flash attention. Block = (head, 128 q-rows); wave w owns
// rows [q0+32w, q0+32w+32) (2 m-frags), steps over s in 64-wide tiles,
// exits at its own causal bound. P transform via wave-private LDS.
// ---------------------------------------------------------------------------
__global__ __launch_bounds__(256) void attn_fa(
    const unsigned short* __restrict__ qh, const unsigned short* __restrict__ kh,
    const unsigned short* __restrict__ vtb, unsigned short* __restrict__ attnb) {
    constexpr int LD = 72;
    __shared__ unsigned short pbuf[4][2][2][16 * LD];   // [wave][parity][mt]
    const int h = blockIdx.y;
    const int qb = (int)gridDim.x - 1 - (int)blockIdx.x;   // longest-first
    const int q0 = qb * 128;
    const int wave = threadIdx.x >> 6, lane = threadIdx.x & 63;
    const int m = lane & 15, quad = lane >> 4;
    const int qrow0 = q0 + wave * 32;

    bf16x8 aq[2][2];
    #pragma unroll
    for (int mt = 0; mt < 2; ++mt) {
        const unsigned short* qptr = qh + ((size_t)h * 2048 + qrow0 + mt * 16 + m) * 64;
        aq[mt][0] = *reinterpret_cast<const bf16x8*>(qptr + quad * 8);
        aq[mt][1] = *reinterpret_cast<const bf16x8*>(qptr + 32 + quad * 8);
    }
    const unsigned short* kbase = kh + (size_t)h * 2048 * 64;
    const unsigned short* vbase = vtb + (size_t)h * 64 * 2048;

    floatx4 o[2][4] = {};
    float mrun[2][4], lrun[2][4];
    #pragma unroll
    for (int mt = 0; mt < 2; ++mt)
        #pragma unroll
        for (int i = 0; i < 4; ++i) { mrun[mt][i] = -1e30f; lrun[mt][i] = 0.0f; }

    const int nsteps = (qrow0 + 95) >> 6;   // covers s <= qrow0+31
    for (int st = 0; st < nsteps; ++st) {
        const int s0 = st * 64;
        floatx4 sc[2][4];
        #pragma unroll
        for (int sg = 0; sg < 4; ++sg) {
            const unsigned short* kr = kbase + (size_t)(s0 + sg * 16 + m) * 64;
            bf16x8 bk0 = *reinterpret_cast<const bf16x8*>(kr + quad * 8);
            bf16x8 bk1 = *reinterpret_cast<const bf16x8*>(kr + 32 + quad * 8);
            #pragma unroll
            for (int mt = 0; mt < 2; ++mt) {
                floatx4 z = {};
                z = mfma16(aq[mt][0], bk0, z);
                z = mfma16(aq[mt][1], bk1, z);
                sc[mt][sg] = z;
            }
        }
        if (s0 + 63 >= qrow0) {              // only near-diagonal steps mask
            #pragma unroll
            for (int mt = 0; mt < 2; ++mt)
                #pragma unroll
                for (int sg = 0; sg < 4; ++sg)
                    #pragma unroll
                    for (int i = 0; i < 4; ++i) {
                        int t = qrow0 + mt * 16 + quad * 4 + i;
                        int s = s0 + sg * 16 + m;
                        sc[mt][sg][i] = (s > t) ? -1e30f : sc[mt][sg][i];
                    }
        }
        float mx[2][4], al[2][4], sum[2][4];
        #pragma unroll
        for (int mt = 0; mt < 2; ++mt)
            #pragma unroll
            for (int i = 0; i < 4; ++i)
                mx[mt][i] = fmaxf(fmaxf(sc[mt][0][i], sc[mt][1][i]),
                                  fmaxf(sc[mt][2][i], sc[mt][3][i]));
        #pragma unroll
        for (int d = 1; d < 16; d <<= 1)
            #pragma unroll
            for (int mt = 0; mt < 2; ++mt)
                #pragma unroll
                for (int i = 0; i < 4; ++i)
                    mx[mt][i] = fmaxf(mx[mt][i], __shfl_xor(mx[mt][i], d, 16));
        #pragma unroll
        for (int mt = 0; mt < 2; ++mt)
            #pragma unroll
            for (int i = 0; i < 4; ++i) {
                float mnew = fmaxf(mrun[mt][i], mx[mt][i]);
                al[mt][i] = __expf(mrun[mt][i] - mnew);
                mrun[mt][i] = mnew;
            }
        #pragma unroll
        for (int mt = 0; mt < 2; ++mt)
            #pragma unroll
            for (int sg = 0; sg < 4; ++sg)
                #pragma unroll
                for (int i = 0; i < 4; ++i)
                    sc[mt][sg][i] = __expf(sc[mt][sg][i] - mrun[mt][i]);
        #pragma unroll
        for (int mt = 0; mt < 2; ++mt)
            #pragma unroll
            for (int i = 0; i < 4; ++i)
                sum[mt][i] = (sc[mt][0][i] + sc[mt][1][i]) + (sc[mt][2][i] + sc[mt][3][i]);
        #pragma unroll
        for (int d = 1; d < 16; d <<= 1)
            #pragma unroll
            for (int mt = 0; mt < 2; ++mt)
                #pragma unroll
                for (int i = 0; i < 4; ++i)
                    sum[mt][i] += __shfl_xor(sum[mt][i], d, 16);
        #pragma unroll
        for (int mt = 0; mt < 2; ++mt)
            #pragma unroll
            for (int i = 0; i < 4; ++i)
                lrun[mt][i] = lrun[mt][i] * al[mt][i] + sum[mt][i];
        #pragma unroll
        for (int mt = 0; mt < 2; ++mt)
            #pragma unroll
            for (int nt = 0; nt < 4; ++nt)
                #pragma unroll
                for (int i = 0; i < 4; ++i)
                    o[mt][nt][i] *= al[mt][i];

        // P: C-layout regs -> wave-private LDS -> A-layout frags (no barrier)
        unsigned short* pb0 = pbuf[wave][st & 1][0];
        unsigned short* pb1 = pbuf[wave][st & 1][1];
        #pragma unroll
        for (int sg = 0; sg < 4; ++sg)
            #pragma unroll
            for (int i = 0; i < 4; ++i) {
                pb0[(quad * 4 + i) * LD + sg * 16 + m] = f2b(sc[0][sg][i]);
                pb1[(quad * 4 + i) * LD + sg * 16 + m] = f2b(sc[1][sg][i]);
            }
        bf16x8 ap[2][2];
        #pragma unroll
        for (int mt = 0; mt < 2; ++mt) {
            ap[mt][0] = *reinterpret_cast<const bf16x8*>(&pbuf[wave][st & 1][mt][m * LD + quad * 8]);
            ap[mt][1] = *reinterpret_cast<const bf16x8*>(&pbuf[wave][st & 1][mt][m * LD + 32 + quad * 8]);
        }
        #pragma unroll
        for (int c = 0; c < 2; ++c)
            #pragma unroll
            for (int nt = 0; nt < 4; ++nt) {
                const unsigned short* vr = vbase + (size_t)(nt * 16 + m) * 2048 + s0 + c * 32 + quad * 8;
                bf16x8 bv = *reinterpret_cast<const bf16x8*>(vr);
                o[0][nt] = mfma16(ap[0][c], bv, o[0][nt]);
                o[1][nt] = mfma16(ap[1][c], bv, o[1][nt]);
            }
    }

    #pragma unroll
    for (int mt = 0; mt < 2; ++mt) {
        float invl[4];
        #pragma unroll
        for (int i = 0; i < 4; ++i) invl[i] = 1.0f / lrun[mt][i];
        #pragma unroll
        for (int nt = 0; nt < 4; ++nt)
            #pragma unroll
            for (int i = 0; i < 4; ++i)
                attnb[(size_t)(qrow0 + mt * 16 + quad * 4 + i) * 2048 + h * 64 + nt * 16 + m]
                    = f2b(o[mt][nt][i] * invl[i]);
    }
}

// ---------------------------------------------------------------------------
extern "C" void kernel_launch(void* const* d_in, const int* in_sizes, int n_in,
                              void* d_out, int out_size, void* d_ws, size_t ws_size,
                              hipStream_t stream) {
    const int*   positions = (const int*)d_in[0];
    const float* hidden    = (const float*)d_in[1];
    const float* Wqkv      = (const float*)d_in[2];
    const float* bqkv      = (const float*)d_in[3];
    const float* Wout      = (const float*)d_in[4];
    const float* bout      = (const float*)d_in[5];
    const float* tau_alpha = (const float*)d_in[6];
    const float* tau_wq    = (const float*)d_in[7];
    const float* tau_wv    = (const float*)d_in[8];

    unsigned char* ws = (unsigned char*)d_ws;
    unsigned short* qkvb    = (unsigned short*)(ws);
    float*          tok_raw = (float*)(ws + 25165824);
    unsigned short* wqb     = (unsigned short*)(ws + 25690112);  // dead after GEMM1
    unsigned short* qh      = (unsigned short*)(ws + 25690112);
    unsigned short* kh      = (unsigned short*)(ws + 34078720);
    unsigned short* vtb     = (unsigned short*)(ws + 42467328);
    unsigned short* attnb   = (unsigned short*)(ws + 50855936);
    unsigned short* hb      = (unsigned short*)(ws + 59244544);
    unsigned short* wob     = (unsigned short*)(ws + 67633152);

    // 0) fp32 -> bf16 conversions
    cvt_f32_bf16<<<2048, 256, 0, stream>>>(hidden, hb, 524288);
    cvt_f32_bf16<<<6144, 256, 0, stream>>>(Wqkv, wqb, 1572864);
    cvt_f32_bf16<<<2048, 256, 0, stream>>>(Wout, wob, 524288);
    // 1) qkvb = hb @ wqb^T + bqkv
    gemm_bf16_bt<true><<<dim3(48, 16), 256, 0, stream>>>(
        hb, wqb, bqkv, qkvb, 2048, 6144, 2048);
    // 2) tok_raw = gelu(qkvb) @ [tau_wq;tau_wv]^T  (split-K)
    hipMemsetAsync(tok_raw, 0, (size_t)2048 * 64 * 4, stream);
    tok_gemm_splitk<256><<<dim3(24, 32), 256, 0, stream>>>(
        qkvb, tau_wq, tau_wv, tok_raw, 6144);
    // 3) gating + RoPE + layouts
    qkv_process<<<dim3(32, 32), 256, 0, stream>>>(
        qkvb, tok_raw, tau_alpha, positions, qh, kh, vtb);
    // 4) flash attention
    attn_fa<<<dim3(16, 32), 256, 0, stream>>>(qh, kh, vtb, attnb);
    // 5) out = attnb @ wob^T + bout
    gemm_bf16_bt<false><<<dim3(16, 16), 256, 0, stream>>>(
        attnb, wob, bout, d_out, 2048, 2048, 2048);
}

// Round 4
// 465.287 us; speedup vs baseline: 2.5582x; 1.0475x over previous
//
#include <hip/hip_runtime.h>
#include <math.h>

// ---------------------------------------------------------------------------
// Moondream3Attention on MI355X (gfx950)
// T=2048, DIM=2048, H=32, HD=64, ROT=32, QKV_DIM=6144
// Pipeline (all-bf16 matmul datapath):
//   0) cvt: hidden->hb, Wqkv->wqb, Wout->wob (fp32->bf16)
//   1) qkvb = hb @ wqb^T + bqkv          (bf16 GEMM, global_load_lds staging)
//   2) tok = gelu(qkvb) @ [tau_wq;tau_wv]^T   (split-K + atomics)
//   3) qkv_process: tau gating + RoPE -> qh(q*1/8),kh [h][t][64], vtb [h][d][s]
//   4) attn_fa: s-split flash attention -> unnormalized partials (bf16 O~, f32 m/l)
//   5) attn_merge: exp-weighted combine -> attnb bf16 [t][2048]
//   6) out = attnb @ wob^T + bout        (bf16 GEMM, fp32 out)
// Workspace (bytes), with liveness-based reuse:
//   region A [0, 33554432): qkvb bf16 [2048][6144] @0, hb bf16 [2048][2048] @25165824
//       -> after qkv_process reused as Opart bf16 [2048 slots][128][64]
//   tok_raw f32 [2048][64]        @ 33554432 (524288)
//   ml      f32 [2048][128][2]    @ 34078720 (2097152)
//   wqb     bf16 [6144][2048]     @ 36175872 (25165824), dead after GEMM1 ->
//     qh    bf16 [32][2048][64]   @ 36175872
//     kh    bf16 [32][2048][64]   @ 44564480
//     vtb   bf16 [32][64][2048]   @ 52953088
//   attnb   bf16 [2048][2048]     @ 61341696 (8388608)
//   wob     bf16 [2048][2048]     @ 69730304 (8388608)   total 78118912
// ---------------------------------------------------------------------------

typedef __bf16 bf16x8 __attribute__((ext_vector_type(8)));
typedef float floatx4 __attribute__((ext_vector_type(4)));
typedef unsigned short ushort8v __attribute__((ext_vector_type(8)));

__device__ __forceinline__ unsigned short f2b(float x) {
    unsigned int b = __float_as_uint(x);
    b = b + 0x7FFFu + ((b >> 16) & 1u);   // round-to-nearest-even
    return (unsigned short)(b >> 16);
}
__device__ __forceinline__ float b2f(unsigned short u) {
    return __uint_as_float(((unsigned int)u) << 16);
}
__device__ __forceinline__ float gelu_f(float x) {
    return 0.5f * x * (1.0f + erff(x * 0.70710678118654752440f));
}
__device__ __forceinline__ floatx4 mfma16(bf16x8 a, bf16x8 b, floatx4 c) {
    return __builtin_amdgcn_mfma_f32_16x16x32_bf16(a, b, c, 0, 0, 0);
}
// async global->LDS, 16B per lane; lane i lands at ldsbase + i*16
__device__ __forceinline__ void gl2lds16(const unsigned short* g, unsigned short* l) {
    __builtin_amdgcn_global_load_lds(
        (__attribute__((address_space(1))) void*)g,
        (__attribute__((address_space(3))) void*)l, 16, 0, 0);
}

// inv_freq[i] = 1e6^(-i/16), i = 0..15
__constant__ float INV_FREQ[16] = {
    1.0f, 0.42169650342858224f, 0.17782794100389228f, 0.074989420933245582f,
    0.031622776601683791f, 0.013335214321633240f, 0.0056234132519034908f,
    0.0023713737056616552f, 0.001f, 4.2169650342858224e-4f,
    1.7782794100389228e-4f, 7.4989420933245582e-5f, 3.1622776601683791e-5f,
    1.3335214321633240e-5f, 5.6234132519034908e-6f, 2.3713737056616552e-6f
};

// s-chunk schedule: tile qt has nc = qt/4+1 chunks of 512 s each (last partial).
// Ordered longest-first: 24 full (8-step) chunks, then 16 finals by length.
__constant__ unsigned char CHUNK_QT[40] = {
    15,15,15, 14,14,14, 13,13,13, 12,12,12, 11,11, 10,10, 9,9, 8,8, 7,6,5,4,
    15,11,7,3, 14,10,6,2, 13,9,5,1, 12,8,4,0};
__constant__ unsigned char CHUNK_C[40] = {
    0,1,2, 0,1,2, 0,1,2, 0,1,2, 0,1, 0,1, 0,1, 0,1, 0,0,0,0,
    3,2,1,0, 3,2,1,0, 3,2,1,0, 3,2,1,0};

// ---------------------------------------------------------------------------
__global__ __launch_bounds__(256) void cvt_f32_bf16(
    const float* __restrict__ src, unsigned short* __restrict__ dst, int n8) {
    int i = blockIdx.x * 256 + threadIdx.x;
    if (i >= n8) return;
    const float4* s = reinterpret_cast<const float4*>(src) + (size_t)i * 2;
    float4 a = s[0], b = s[1];
    ushort8v r;
    r[0] = f2b(a.x); r[1] = f2b(a.y); r[2] = f2b(a.z); r[3] = f2b(a.w);
    r[4] = f2b(b.x); r[5] = f2b(b.y); r[6] = f2b(b.z); r[7] = f2b(b.w);
    *(reinterpret_cast<ushort8v*>(dst) + i) = r;
}

// ---------------------------------------------------------------------------
// bf16 GEMM: C[M,N] = A[M,K] @ B[N,K]^T + bias[N].  128x128 tile, BK=64.
// Staging via global_load_lds (16B/lane). LDS layout:
//   addr(r,c8) = (r>>3)*1024B + c8*128B + (r&7)*16B  (r=tile row, c8=k/8)
// ---------------------------------------------------------------------------
template <bool OUT_BF16>
__global__ __launch_bounds__(256) void gemm_bf16_bt(
    const unsigned short* __restrict__ A, const unsigned short* __restrict__ B,
    const float* __restrict__ bias, void* __restrict__ Cout,
    int M, int N, int K) {
    __shared__ unsigned short As[128 * 64];
    __shared__ unsigned short Bs[128 * 64];
    const int tid = threadIdx.x;
    const int wave = tid >> 6, lane = tid & 63;
    const int row16 = lane & 15, quad = lane >> 4;
    const int wm = (wave >> 1) * 64, wn = (wave & 1) * 64;
    const int bm0 = blockIdx.y * 128, bn0 = blockIdx.x * 128;
    const int rl = lane & 7, cl = lane >> 3;

    floatx4 acc[4][4] = {};

    for (int k0 = 0; k0 < K; k0 += 64) {
        __syncthreads();                       // prev iter's frag reads done
        #pragma unroll
        for (int j = 0; j < 4; ++j) {
            int inst = wave * 4 + j;           // covers tile rows inst*8..+8
            const unsigned short* ga = A + (size_t)(bm0 + inst * 8 + rl) * K + k0 + cl * 8;
            gl2lds16(ga, &As[inst * 512 + lane * 8]);
            const unsigned short* gb = B + (size_t)(bn0 + inst * 8 + rl) * K + k0 + cl * 8;
            gl2lds16(gb, &Bs[inst * 512 + lane * 8]);
        }
        __syncthreads();                       // drains vmcnt -> data landed

        #pragma unroll
        for (int ks = 0; ks < 2; ++ks) {
            bf16x8 af[4], bfr[4];
            #pragma unroll
            for (int mt = 0; mt < 4; ++mt) {
                int r = wm + mt * 16 + row16;
                af[mt] = *reinterpret_cast<const bf16x8*>(
                    &As[(r >> 3) * 512 + (ks * 4 + quad) * 64 + (r & 7) * 8]);
            }
            #pragma unroll
            for (int nt = 0; nt < 4; ++nt) {
                int r = wn + nt * 16 + row16;
                bfr[nt] = *reinterpret_cast<const bf16x8*>(
                    &Bs[(r >> 3) * 512 + (ks * 4 + quad) * 64 + (r & 7) * 8]);
            }
            #pragma unroll
            for (int mt = 0; mt < 4; ++mt)
                #pragma unroll
                for (int nt = 0; nt < 4; ++nt)
                    acc[mt][nt] = mfma16(af[mt], bfr[nt], acc[mt][nt]);
        }
    }

    #pragma unroll
    for (int mt = 0; mt < 4; ++mt) {
        #pragma unroll
        for (int nt = 0; nt < 4; ++nt) {
            int gc = bn0 + wn + nt * 16 + row16;
            float bv = bias[gc];
            int gr0 = bm0 + wm + mt * 16 + quad * 4;
            #pragma unroll
            for (int i = 0; i < 4; ++i) {
                float v = acc[mt][nt][i] + bv;
                if (OUT_BF16)
                    ((unsigned short*)Cout)[(size_t)(gr0 + i) * N + gc] = f2b(v);
                else
                    ((float*)Cout)[(size_t)(gr0 + i) * N + gc] = v;
            }
        }
    }
}

// ---------------------------------------------------------------------------
// tok GEMM split-K: C[2048,64] += gelu(qkvb) @ [Bq;Bv]^T; C pre-zeroed.
// ---------------------------------------------------------------------------
template <int KSPLIT>
__global__ __launch_bounds__(256) void tok_gemm_splitk(
    const unsigned short* __restrict__ A, const float* __restrict__ Bq,
    const float* __restrict__ Bv, float* __restrict__ C, int K) {
    constexpr int LDT = 72;
    __shared__ unsigned short As[64 * LDT];
    __shared__ unsigned short Bs[64 * LDT];
    const int tid = threadIdx.x;
    const int wave = tid >> 6, lane = tid & 63;
    const int row16 = lane & 15, quad = lane >> 4;
    const int wm = (wave >> 1) * 32, wn = (wave & 1) * 32;
    const int bm0 = blockIdx.y * 64;
    const int kbeg = blockIdx.x * KSPLIT;

    floatx4 acc[2][2] = {};

    for (int k0 = kbeg; k0 < kbeg + KSPLIT; k0 += 64) {
        #pragma unroll
        for (int it = 0; it < 2; ++it) {
            int i = tid + it * 256;
            int r = i >> 3, c8 = i & 7;
            ushort8v a = *reinterpret_cast<const ushort8v*>(
                A + (size_t)(bm0 + r) * K + k0 + c8 * 8);
            ushort8v g;
            #pragma unroll
            for (int j = 0; j < 8; ++j) g[j] = f2b(gelu_f(b2f(a[j])));
            *reinterpret_cast<ushort8v*>(&As[r * LDT + c8 * 8]) = g;

            const float* brow = (r < 32) ? (Bq + (size_t)r * K) : (Bv + (size_t)(r - 32) * K);
            float4 w0 = *reinterpret_cast<const float4*>(brow + k0 + c8 * 8);
            float4 w1 = *reinterpret_cast<const float4*>(brow + k0 + c8 * 8 + 4);
            ushort8v wb;
            wb[0] = f2b(w0.x); wb[1] = f2b(w0.y); wb[2] = f2b(w0.z); wb[3] = f2b(w0.w);
            wb[4] = f2b(w1.x); wb[5] = f2b(w1.y); wb[6] = f2b(w1.z); wb[7] = f2b(w1.w);
            *reinterpret_cast<ushort8v*>(&Bs[r * LDT + c8 * 8]) = wb;
        }
        __syncthreads();

        #pragma unroll
        for (int ks = 0; ks < 2; ++ks) {
            bf16x8 af[2], bfr[2];
            #pragma unroll
            for (int mt = 0; mt < 2; ++mt)
                af[mt] = *reinterpret_cast<const bf16x8*>(
                    &As[(wm + mt * 16 + row16) * LDT + ks * 32 + quad * 8]);
            #pragma unroll
            for (int nt = 0; nt < 2; ++nt)
                bfr[nt] = *reinterpret_cast<const bf16x8*>(
                    &Bs[(wn + nt * 16 + row16) * LDT + ks * 32 + quad * 8]);
            #pragma unroll
            for (int mt = 0; mt < 2; ++mt)
                #pragma unroll
                for (int nt = 0; nt < 2; ++nt)
                    acc[mt][nt] = mfma16(af[mt], bfr[nt], acc[mt][nt]);
        }
        __syncthreads();
    }

    #pragma unroll
    for (int mt = 0; mt < 2; ++mt)
        #pragma unroll
        for (int nt = 0; nt < 2; ++nt) {
            int gc = wn + nt * 16 + row16;
            int gr0 = bm0 + wm + mt * 16 + quad * 4;
            #pragma unroll
            for (int i = 0; i < 4; ++i)
                atomicAdd(&C[(size_t)(gr0 + i) * 64 + gc], acc[mt][nt][i]);
        }
}

// ---------------------------------------------------------------------------
// tau gating + RoPE + layout transforms (qkv bf16; q pre-scaled by 1/8).
// ---------------------------------------------------------------------------
__global__ __launch_bounds__(256) void qkv_process(
    const unsigned short* __restrict__ qkvb, const float* __restrict__ tok_raw,
    const float* __restrict__ tau_alpha, const int* __restrict__ positions,
    unsigned short* __restrict__ qh, unsigned short* __restrict__ kh,
    unsigned short* __restrict__ vtb) {
    const int h = blockIdx.y;
    const int t0 = blockIdx.x * 64;
    const int tid = threadIdx.x;
    __shared__ float vtr[64][65];
    __shared__ float tauq_s[64], tauv_s[64];

    if (tid < 64) {
        int t = t0 + tid;
        float pos = (float)positions[t];
        float pl = logf(fmaxf(pos + 1.0f, 1e-6f));
        float a = tau_alpha[h];
        float tp = 0.5f + 1.0f / (1.0f + __expf(-a * pl));
        tauq_s[tid] = tanhf(tok_raw[t * 64 + h]) + tp;
        tauv_s[tid] = tanhf(tok_raw[t * 64 + 32 + h]) + tp;
    }
    __syncthreads();

    #pragma unroll 4
    for (int it = 0; it < 16; ++it) {
        int i = tid + it * 256;
        int tl = i >> 6, d = i & 63;
        int t = t0 + tl;
        const unsigned short* row = qkvb + (size_t)t * 6144 + h * 64;
        float qv = b2f(row[d]);
        float kv = b2f(row[2048 + d]);
        float vv = b2f(row[4096 + d]);
        float tq = tauq_s[tl];
        float qo = qv * tq, ko = kv;
        if (d < 32) {
            int fi = d & 15;
            float ang = (float)positions[t] * INV_FREQ[fi];
            float s, c;
            sincosf(ang, &s, &c);
            float qp = b2f(row[d ^ 16]) * tq;
            float kp = b2f(row[2048 + (d ^ 16)]);
            if (d < 16) { qo = qv * tq * c - qp * s; ko = kv * c - kp * s; }
            else        { qo = qv * tq * c + qp * s; ko = kv * c + kp * s; }
        }
        size_t ob = ((size_t)h * 2048 + t) * 64 + d;
        qh[ob] = f2b(qo * 0.125f);   // fold softmax scale into Q
        kh[ob] = f2b(ko);
        vtr[d][tl] = vv * tauv_s[tl];
    }
    __syncthreads();
    #pragma unroll 4
    for (int it = 0; it < 16; ++it) {
        int i = tid + it * 256;
        int d = i >> 6, tl = i & 63;
        vtb[((size_t)h * 64 + d) * 2048 + t0 + tl] = f2b(vtr[d][tl]);
    }
}

// ---------------------------------------------------------------------------
// s-split flash attention. Block = (chunk idx, head); chunk = (qt, c) covers
// q-rows [128qt, 128qt+128) x s in [512c, 512c+512) clipped causally.
// Wave w owns 32 q-rows. Writes unnormalized O~ (bf16) + per-row m,l (f32).
// ---------------------------------------------------------------------------
__global__ __launch_bounds__(256) void attn_fa(
    const unsigned short* __restrict__ qh, const unsigned short* __restrict__ kh,
    const unsigned short* __restrict__ vtb, unsigned short* __restrict__ Opart,
    float* __restrict__ ml) {
    constexpr int LD = 72;
    __shared__ unsigned short pbuf[4][2][2][16 * LD];   // [wave][parity][mt]
    const int h = blockIdx.y;
    const int qt = CHUNK_QT[blockIdx.x], ch = CHUNK_C[blockIdx.x];
    const int q0 = qt * 128;
    const int slot = (h * 16 + qt) * 4 + ch;
    const int wave = threadIdx.x >> 6, lane = threadIdx.x & 63;
    const int m = lane & 15, quad = lane >> 4;
    const int qrow0 = q0 + wave * 32;
    const int sbeg = ch * 512;
    const int send = min(sbeg + 512, qrow0 + 32);

    bf16x8 aq[2][2];
    #pragma unroll
    for (int mt = 0; mt < 2; ++mt) {
        const unsigned short* qptr = qh + ((size_t)h * 2048 + qrow0 + mt * 16 + m) * 64;
        aq[mt][0] = *reinterpret_cast<const bf16x8*>(qptr + quad * 8);
        aq[mt][1] = *reinterpret_cast<const bf16x8*>(qptr + 32 + quad * 8);
    }
    const unsigned short* kbase = kh + (size_t)h * 2048 * 64;
    const unsigned short* vbase = vtb + (size_t)h * 64 * 2048;

    floatx4 o[2][4] = {};
    float mrun[2][4], lrun[2][4];
    #pragma unroll
    for (int mt = 0; mt < 2; ++mt)
        #pragma unroll
        for (int i = 0; i < 4; ++i) { mrun[mt][i] = -1e30f; lrun[mt][i] = 0.0f; }

    for (int s0 = sbeg; s0 < send; s0 += 64) {
        floatx4 sc[2][4];
        #pragma unroll
        for (int sg = 0; sg < 4; ++sg) {
            const unsigned short* kr = kbase + (size_t)(s0 + sg * 16 + m) * 64;
            bf16x8 bk0 = *reinterpret_cast<const bf16x8*>(kr + quad * 8);
            bf16x8 bk1 = *reinterpret_cast<const bf16x8*>(kr + 32 + quad * 8);
            #pragma unroll
            for (int mt = 0; mt < 2; ++mt) {
                floatx4 z = {};
                z = mfma16(aq[mt][0], bk0, z);
                z = mfma16(aq[mt][1], bk1, z);
                sc[mt][sg] = z;
            }
        }
        if (s0 + 63 > qrow0) {               // only near-diagonal steps mask
            #pragma unroll
            for (int mt = 0; mt < 2; ++mt)
                #pragma unroll
                for (int sg = 0; sg < 4; ++sg)
                    #pragma unroll
                    for (int i = 0; i < 4; ++i) {
                        int t = qrow0 + mt * 16 + quad * 4 + i;
                        int s = s0 + sg * 16 + m;
                        sc[mt][sg][i] = (s > t) ? -1e30f : sc[mt][sg][i];
                    }
        }
        float mx[2][4], al[2][4], sum[2][4];
        #pragma unroll
        for (int mt = 0; mt < 2; ++mt)
            #pragma unroll
            for (int i = 0; i < 4; ++i)
                mx[mt][i] = fmaxf(fmaxf(sc[mt][0][i], sc[mt][1][i]),
                                  fmaxf(sc[mt][2][i], sc[mt][3][i]));
        #pragma unroll
        for (int d = 1; d < 16; d <<= 1)
            #pragma unroll
            for (int mt = 0; mt < 2; ++mt)
                #pragma unroll
                for (int i = 0; i < 4; ++i)
                    mx[mt][i] = fmaxf(mx[mt][i], __shfl_xor(mx[mt][i], d, 16));
        #pragma unroll
        for (int mt = 0; mt < 2; ++mt)
            #pragma unroll
            for (int i = 0; i < 4; ++i) {
                float mnew = fmaxf(mrun[mt][i], mx[mt][i]);
                al[mt][i] = __expf(mrun[mt][i] - mnew);
                mrun[mt][i] = mnew;
            }
        #pragma unroll
        for (int mt = 0; mt < 2; ++mt)
            #pragma unroll
            for (int sg = 0; sg < 4; ++sg)
                #pragma unroll
                for (int i = 0; i < 4; ++i)
                    sc[mt][sg][i] = __expf(sc[mt][sg][i] - mrun[mt][i]);
        #pragma unroll
        for (int mt = 0; mt < 2; ++mt)
            #pragma unroll
            for (int i = 0; i < 4; ++i)
                sum[mt][i] = (sc[mt][0][i] + sc[mt][1][i]) + (sc[mt][2][i] + sc[mt][3][i]);
        #pragma unroll
        for (int d = 1; d < 16; d <<= 1)
            #pragma unroll
            for (int mt = 0; mt < 2; ++mt)
                #pragma unroll
                for (int i = 0; i < 4; ++i)
                    sum[mt][i] += __shfl_xor(sum[mt][i], d, 16);
        #pragma unroll
        for (int mt = 0; mt < 2; ++mt)
            #pragma unroll
            for (int i = 0; i < 4; ++i)
                lrun[mt][i] = lrun[mt][i] * al[mt][i] + sum[mt][i];
        #pragma unroll
        for (int mt = 0; mt < 2; ++mt)
            #pragma unroll
            for (int nt = 0; nt < 4; ++nt)
                #pragma unroll
                for (int i = 0; i < 4; ++i)
                    o[mt][nt][i] *= al[mt][i];

        // P: C-layout regs -> wave-private LDS -> A-layout frags (no barrier)
        const int par = (s0 >> 6) & 1;
        unsigned short* pb0 = pbuf[wave][par][0];
        unsigned short* pb1 = pbuf[wave][par][1];
        #pragma unroll
        for (int sg = 0; sg < 4; ++sg)
            #pragma unroll
            for (int i = 0; i < 4; ++i) {
                pb0[(quad * 4 + i) * LD + sg * 16 + m] = f2b(sc[0][sg][i]);
                pb1[(quad * 4 + i) * LD + sg * 16 + m] = f2b(sc[1][sg][i]);
            }
        bf16x8 ap[2][2];
        #pragma unroll
        for (int mt = 0; mt < 2; ++mt) {
            ap[mt][0] = *reinterpret_cast<const bf16x8*>(&pbuf[wave][par][mt][m * LD + quad * 8]);
            ap[mt][1] = *reinterpret_cast<const bf16x8*>(&pbuf[wave][par][mt][m * LD + 32 + quad * 8]);
        }
        #pragma unroll
        for (int c = 0; c < 2; ++c)
            #pragma unroll
            for (int nt = 0; nt < 4; ++nt) {
                const unsigned short* vr = vbase + (size_t)(nt * 16 + m) * 2048 + s0 + c * 32 + quad * 8;
                bf16x8 bv = *reinterpret_cast<const bf16x8*>(vr);
                o[0][nt] = mfma16(ap[0][c], bv, o[0][nt]);
                o[1][nt] = mfma16(ap[1][c], bv, o[1][nt]);
            }
    }

    // epilogue: unnormalized partials
    #pragma unroll
    for (int mt = 0; mt < 2; ++mt) {
        #pragma unroll
        for (int nt = 0; nt < 4; ++nt)
            #pragma unroll
            for (int i = 0; i < 4; ++i)
                Opart[((size_t)slot * 128 + wave * 32 + mt * 16 + quad * 4 + i) * 64 + nt * 16 + m]
                    = f2b(o[mt][nt][i]);
        if (m == 0) {
            #pragma unroll
            for (int i = 0; i < 4; ++i) {
                size_t rr = (size_t)slot * 128 + wave * 32 + mt * 16 + quad * 4 + i;
                ml[rr * 2]     = mrun[mt][i];
                ml[rr * 2 + 1] = lrun[mt][i];
            }
        }
    }
}

// ---------------------------------------------------------------------------
// Merge s-split partials: O = sum_c e^{m_c-m*} O~_c / sum_c e^{m_c-m*} l_c.
// Block = (qt, h); thread t: row t/2, cols (t&1)*32 .. +32.
// ---------------------------------------------------------------------------
__global__ __launch_bounds__(256) void attn_merge(
    const unsigned short* __restrict__ Opart, const float* __restrict__ ml,
    unsigned short* __restrict__ attnb) {
    const int qt = blockIdx.x, h = blockIdx.y;
    const int nc = qt / 4 + 1;
    const int tid = threadIdx.x;
    const int r = tid >> 1, dh = (tid & 1) * 32;
    const int bs = (h * 16 + qt) * 4;

    float mv[4], lv[4], w[4], mstar = -1e30f;
    #pragma unroll
    for (int c = 0; c < 4; ++c) {
        if (c < nc) {
            mv[c] = ml[((size_t)(bs + c) * 128 + r) * 2];
            lv[c] = ml[((size_t)(bs + c) * 128 + r) * 2 + 1];
            mstar = fmaxf(mstar, mv[c]);
        }
    }
    float denom = 0.0f;
    #pragma unroll
    for (int c = 0; c < 4; ++c)
        if (c < nc) { w[c] = __expf(mv[c] - mstar); denom += w[c] * lv[c]; }
    float inv = 1.0f / denom;

    float acc[32] = {};
    #pragma unroll
    for (int c = 0; c < 4; ++c) {
        if (c < nc) {
            const unsigned short* op = Opart + ((size_t)(bs + c) * 128 + r) * 64 + dh;
            #pragma unroll
            for (int j = 0; j < 4; ++j) {
                ushort8v v = *reinterpret_cast<const ushort8v*>(op + j * 8);
                #pragma unroll
                for (int k = 0; k < 8; ++k)
                    acc[j * 8 + k] += w[c] * b2f(v[k]);
            }
        }
    }
    unsigned short* dst = attnb + (size_t)(qt * 128 + r) * 2048 + h * 64 + dh;
    #pragma unroll
    for (int j = 0; j < 4; ++j) {
        ushort8v v;
        #pragma unroll
        for (int k = 0; k < 8; ++k) v[k] = f2b(acc[j * 8 + k] * inv);
        *reinterpret_cast<ushort8v*>(dst + j * 8) = v;
    }
}

// ---------------------------------------------------------------------------
extern "C" void kernel_launch(void* const* d_in, const int* in_sizes, int n_in,
                              void* d_out, int out_size, void* d_ws, size_t ws_size,
                              hipStream_t stream) {
    const int*   positions = (const int*)d_in[0];
    const float* hidden    = (const float*)d_in[1];
    const float* Wqkv      = (const float*)d_in[2];
    const float* bqkv      = (const float*)d_in[3];
    const float* Wout      = (const float*)d_in[4];
    const float* bout      = (const float*)d_in[5];
    const float* tau_alpha = (const float*)d_in[6];
    const float* tau_wq    = (const float*)d_in[7];
    const float* tau_wv    = (const float*)d_in[8];

    unsigned char* ws = (unsigned char*)d_ws;
    unsigned short* qkvb    = (unsigned short*)(ws);             // region A
    unsigned short* hb      = (unsigned short*)(ws + 25165824);  // region A
    unsigned short* Opart   = (unsigned short*)(ws);             // reuses A
    float*          tok_raw = (float*)(ws + 33554432);
    float*          ml      = (float*)(ws + 34078720);
    unsigned short* wqb     = (unsigned short*)(ws + 36175872);  // dead after GEMM1
    unsigned short* qh      = (unsigned short*)(ws + 36175872);
    unsigned short* kh      = (unsigned short*)(ws + 44564480);
    unsigned short* vtb     = (unsigned short*)(ws + 52953088);
    unsigned short* attnb   = (unsigned short*)(ws + 61341696);
    unsigned short* wob     = (unsigned short*)(ws + 69730304);

    // 0) fp32 -> bf16 conversions
    cvt_f32_bf16<<<2048, 256, 0, stream>>>(hidden, hb, 524288);
    cvt_f32_bf16<<<6144, 256, 0, stream>>>(Wqkv, wqb, 1572864);
    cvt_f32_bf16<<<2048, 256, 0, stream>>>(Wout, wob, 524288);
    // 1) qkvb = hb @ wqb^T + bqkv
    gemm_bf16_bt<true><<<dim3(48, 16), 256, 0, stream>>>(
        hb, wqb, bqkv, qkvb, 2048, 6144, 2048);
    // 2) tok_raw = gelu(qkvb) @ [tau_wq;tau_wv]^T  (split-K)
    hipMemsetAsync(tok_raw, 0, (size_t)2048 * 64 * 4, stream);
    tok_gemm_splitk<256><<<dim3(24, 32), 256, 0, stream>>>(
        qkvb, tau_wq, tau_wv, tok_raw, 6144);
    // 3) gating + RoPE + layouts
    qkv_process<<<dim3(32, 32), 256, 0, stream>>>(
        qkvb, tok_raw, tau_alpha, positions, qh, kh, vtb);
    // 4) s-split flash attention -> partials
    attn_fa<<<dim3(40, 32), 256, 0, stream>>>(qh, kh, vtb, Opart, ml);
    // 5) merge partials -> attnb
    attn_merge<<<dim3(16, 32), 256, 0, stream>>>(Opart, ml, attnb);
    // 6) out = attnb @ wob^T + bout
    gemm_bf16_bt<false><<<dim3(16, 16), 256, 0, stream>>>(
        attnb, wob, bout, d_out, 2048, 2048, 2048);
}